// Round 14
// baseline (102.582 us; speedup 1.0000x reference)
//
#include <hip/hip_runtime.h>
#include <stdint.h>

#pragma clang fp contract(off)

#define NB   8
#define NM   1024
#define NGT  100
#define RPB  16                  // rois per block
#define GRID (NB * NM / RPB)     // 512 blocks, image-aligned
#define MAGIC 0x13572468u

typedef uint32_t u32;
typedef unsigned short u16;
typedef unsigned long long u64;

// ---------- Threefry-2x32 block (exact JAX schedule) ----------
__device__ __forceinline__ void tf2x32(u32 k0, u32 k1, u32 x0, u32 x1, u32& o0, u32& o1) {
    u32 k2 = k0 ^ k1 ^ 0x1BD11BDAu;
#define TFR(r) { x0 += x1; x1 = (x1 << r) | (x1 >> (32 - r)); x1 ^= x0; }
    x0 += k0; x1 += k1;
    TFR(13) TFR(15) TFR(26) TFR(6)
    x0 += k1; x1 += k2 + 1u;
    TFR(17) TFR(29) TFR(16) TFR(24)
    x0 += k2; x1 += k0 + 2u;
    TFR(13) TFR(15) TFR(26) TFR(6)
    x0 += k0; x1 += k1 + 3u;
    TFR(17) TFR(29) TFR(16) TFR(24)
    x0 += k1; x1 += k2 + 4u;
    TFR(13) TFR(15) TFR(26) TFR(6)
    x0 += k2; x1 += k0 + 5u;
#undef TFR
    o0 = x0; o1 = x1;
}

__device__ __forceinline__ u32 tf_bits32(u32 k0, u32 k1, u32 i) {
    u32 o0, o1;
    tf2x32(k0, k1, 0u, i, o0, o1);
    return o0 ^ o1;
}

__device__ __forceinline__ float bits2unif(u32 bits) {
    return __uint_as_float((bits >> 9) | 0x3f800000u) - 1.0f;
}

__device__ __forceinline__ void image_keys(int b, u32 k[4][2]) {
    u32 kb0, kb1;
    tf2x32(0u, 42u, 0u, (u32)b, kb0, kb1);               // split(key(42), 8)[b]
    for (int i = 0; i < 4; i++)
        tf2x32(kb0, kb1, 0u, (u32)i, k[i][0], k[i][1]);  // split(key_b, 4)[i]
}

__device__ __forceinline__ float unif_at(const u32 k[2], int i) {
    return bits2unif(tf_bits32(k[0], k[1], (u32)i));
}

// ---------- numpy pairwise blocked sum over exactly 24 f32 terms ----------
__device__ __forceinline__ float np_pw24(const float* t) {
    float r0 = (t[0] + t[8])  + t[16];
    float r1 = (t[1] + t[9])  + t[17];
    float r2 = (t[2] + t[10]) + t[18];
    float r3 = (t[3] + t[11]) + t[19];
    float r4 = (t[4] + t[12]) + t[20];
    float r5 = (t[5] + t[13]) + t[21];
    float r6 = (t[6] + t[14]) + t[22];
    float r7 = (t[7] + t[15]) + t[23];
    return ((r0 + r1) + (r2 + r3)) + ((r4 + r5) + (r6 + r7));
}

// monotone float -> u32 order map (no NaNs in the angle stream)
__device__ __forceinline__ u32 fkey(float f) {
    u32 b = __float_as_uint(f);
    return (b & 0x80000000u) ? ~b : (b | 0x80000000u);
}

// Batcher odd-even mergesort network, compile-time N, key + (x,y) payload
template<int N>
__device__ __forceinline__ void sortnet(u64* key, float* x, float* y) {
#define CE(A, B) { \
        u64 ka = key[A], kb = key[B]; \
        bool sw = ka > kb; \
        float xa = x[A], xb = x[B], ya = y[A], yb = y[B]; \
        key[A] = sw ? kb : ka; key[B] = sw ? ka : kb; \
        x[A]  = sw ? xb : xa; x[B]  = sw ? xa : xb; \
        y[A]  = sw ? yb : ya; y[B]  = sw ? ya : yb; }
    #pragma unroll
    for (int pp = 1; pp < N; pp <<= 1) {
        #pragma unroll
        for (int kq = pp; kq >= 1; kq >>= 1) {
            #pragma unroll
            for (int jq = kq % pp; jq + kq < N; jq += 2 * kq) {
                #pragma unroll
                for (int iq = 0; iq < kq; iq++) {
                    if (iq + jq + kq < N) {
                        if ((iq + jq) / (2 * pp) == (iq + jq + kq) / (2 * pp)) {
                            CE(iq + jq, iq + jq + kq);
                        }
                    }
                }
            }
        }
    }
#undef CE
}

// ---------- rotated 3D IoU (R10-R13 bit-verified: absmax 0.0 end-to-end) ----------
__device__ __forceinline__ float iou_slow(const float* a, const float* b) {
    float oh = fminf(a[2] + a[5] * 0.5f, b[2] + b[5] * 0.5f)
             - fmaxf(a[2] - a[5] * 0.5f, b[2] - b[5] * 0.5f);
    oh = fmaxf(oh, 0.0f);
    float va = a[3] * a[4] * a[5];
    float vb = b[3] * b[4] * b[5];

    float ca = cosf(a[6]), sa = sinf(a[6]);
    float cb = cosf(b[6]), sb = sinf(b[6]);
    const float SX[4] = {1.f, 1.f, -1.f, -1.f};
    const float SY[4] = {1.f, -1.f, -1.f, 1.f};
    float axp[4], ayp[4], bxp[4], byp[4];
    float hx = a[3] * 0.5f, hy = a[4] * 0.5f;
    #pragma unroll
    for (int q = 0; q < 4; q++) {
        float lx = SX[q] * hx, ly = SY[q] * hy;
        axp[q] = lx * ca - ly * sa + a[0];
        ayp[q] = lx * sa + ly * ca + a[1];
    }
    hx = b[3] * 0.5f; hy = b[4] * 0.5f;
    #pragma unroll
    for (int q = 0; q < 4; q++) {
        float lx = SX[q] * hx, ly = SY[q] * hy;
        bxp[q] = lx * cb - ly * sb + b[0];
        byp[q] = lx * sb + ly * cb + b[1];
    }

    float vx[24], vy[24];
    u32 vm = 0;
    #pragma unroll
    for (int i = 0; i < 4; i++) {
        float a1x = axp[i], a1y = ayp[i];
        float d1x = axp[(i + 1) & 3] - a1x, d1y = ayp[(i + 1) & 3] - a1y;
        #pragma unroll
        for (int j = 0; j < 4; j++) {
            int pos = i * 4 + j;
            float b1x = bxp[j], b1y = byp[j];
            float d2x = bxp[(j + 1) & 3] - b1x, d2y = byp[(j + 1) & 3] - b1y;
            float fx = b1x - a1x, fy = b1y - a1y;
            float den = d1x * d2y - d1y * d2x;
            bool val = false; float px = 0.f, py = 0.f;
            if (fabsf(den) > 1e-8f) {
                float tt = (fx * d2y - fy * d2x) / den;
                float uu = (fx * d1y - fy * d1x) / den;
                if (tt >= 0.f && tt <= 1.f && uu >= 0.f && uu <= 1.f) {
                    val = true; px = a1x + tt * d1x; py = a1y + tt * d1y;
                }
            }
            vx[pos] = val ? px : 0.f;
            vy[pos] = val ? py : 0.f;
            vm |= (val ? 1u : 0u) << pos;
        }
    }
    #pragma unroll
    for (int q = 0; q < 4; q++) {
        float rx = axp[q] - b[0], ry = ayp[q] - b[1];
        float lx = rx * cb + ry * sb, ly = -rx * sb + ry * cb;
        bool v = (fabsf(lx) <= b[3] * 0.5f + 1e-6f) && (fabsf(ly) <= b[4] * 0.5f + 1e-6f);
        vx[16 + q] = v ? axp[q] : 0.f; vy[16 + q] = v ? ayp[q] : 0.f;
        vm |= (v ? 1u : 0u) << (16 + q);
    }
    #pragma unroll
    for (int q = 0; q < 4; q++) {
        float rx = bxp[q] - a[0], ry = byp[q] - a[1];
        float lx = rx * ca + ry * sa, ly = -rx * sa + ry * ca;
        bool v = (fabsf(lx) <= a[3] * 0.5f + 1e-6f) && (fabsf(ly) <= a[4] * 0.5f + 1e-6f);
        vx[20 + q] = v ? bxp[q] : 0.f; vy[20 + q] = v ? byp[q] : 0.f;
        vm |= (v ? 1u : 0u) << (20 + q);
    }

    int nv = __popc(vm);
    if (nv <= 2) return 0.0f;   // bit-exact: np pairwise shoelace of <=2 pts is 0

    float cx = np_pw24(vx) / (float)nv;
    float cy = np_pw24(vy) / (float)nv;

    float sx[24], sy[24];
    #pragma unroll
    for (int p = 0; p < 24; p++) {
        bool v = (vm >> p) & 1u;
        sx[p] = v ? (vx[p] - cx) : 0.f;
        sy[p] = v ? (vy[p] - cy) : 0.f;
    }

    float area;
    if (nv <= 8) {
        // common path: compact-to-8 (static select-gather), 8-net, ALU only
        float gx[8], gy[8]; u32 gp[8];
        #pragma unroll
        for (int i = 0; i < 8; i++) { gx[i] = 0.f; gy[i] = 0.f; gp[i] = 0u; }
        u32 pref = 0;
        #pragma unroll
        for (int p = 0; p < 24; p++) {
            bool v = (vm >> p) & 1u;
            u32 pos = pref;
            pref += v ? 1u : 0u;
            #pragma unroll
            for (int i = 0; i < 8; i++) {
                bool take = v && (pos == (u32)i);
                gx[i] += take ? sx[p] : 0.f;
                gy[i] += take ? sy[p] : 0.f;
                gp[i] |= take ? (u32)p : 0u;
            }
        }
        u64 key[8];
        #pragma unroll
        for (int i = 0; i < 8; i++) {
            float ang = atan2f(gy[i], gx[i]);
            key[i] = (i < nv) ? ((((u64)fkey(ang)) << 32) | (u64)gp[i]) : ~0ull;
        }
        sortnet<8>(key, gx, gy);
        float st[24];
        #pragma unroll
        for (int i = 0; i < 24; i++) st[i] = 0.f;
        #pragma unroll
        for (int i = 0; i < 8; i++) {
            int n1 = (i + 1 < 8) ? (i + 1) : 0;
            bool wrap = (i + 1 >= nv);
            float nx2 = wrap ? gx[0] : gx[n1];
            float ny2 = wrap ? gy[0] : gy[n1];
            float c = gx[i] * ny2 - gy[i] * nx2;
            st[i] = (i < nv) ? c : 0.0f;
        }
        area = 0.5f * fabsf(np_pw24(st));
    } else {
        // rare fallback (nv > 8): full 24-sort (R9-verified)
        u64 key[24];
        #pragma unroll
        for (int p = 0; p < 24; p++) {
            bool v = (vm >> p) & 1u;
            float ang = atan2f(sy[p], sx[p]);
            u32 hi = v ? fkey(ang) : 0xFFFFFFFFu;
            key[p] = ((u64)hi << 32) | (u64)(u32)p;
        }
        sortnet<24>(key, sx, sy);
        float st[24];
        #pragma unroll
        for (int i = 0; i < 24; i++) {
            const int nidx = (i + 1 < 24) ? (i + 1) : 0;
            bool wrap = (i + 1 >= nv);
            float nx2 = wrap ? sx[0] : sx[nidx];
            float ny2 = wrap ? sy[0] : sy[nidx];
            float c = sx[i] * ny2 - sy[i] * nx2;
            st[i] = (i < nv) ? c : 0.0f;
        }
        area = 0.5f * fabsf(np_pw24(st));
    }
    float inter = area * oh;
    return inter / fmaxf(va + vb - inter, 1e-6f);
}

// ---------- output layout (f32, return order) ----------
#define O_ROIS 0
#define O_GT   7168
#define O_IOU  15360
#define O_SC   16384
#define O_LB   17408
#define O_CLS  18432
#define O_REG  19456

// LDS overlay: reject/slow phase vs sampling phase (never simultaneous)
union SMem {
    struct {
        float gt8[NGT * 8];
        float raw[RPB * 7];
        float gx[NGT], gy[NGT], gzh[NGT], gzl[NGT], grb[NGT];
        float rx[RPB], ry[RPB], rzh[RPB], rzl[RPB], rr[RPB];
        u16   list[RPB * NGT];
        u64   mob16[RPB];
    } R;
    struct {
        float mo[NM], ufg[NM];
        int   fgc[NM], hardc[NM], easyc[NM], perm[NM];
        int   wcf[16], wch[16], wce[16];
        int   nfg, nhard, neasy;
    } S;
};

// ---------- single fused kernel: 512 blocks x 64 threads (1 wave/block) ----------
__global__ __launch_bounds__(64, 1) void rcnn_fused(
    const float* __restrict__ rois, const float* __restrict__ gts,
    const float* __restrict__ scores, const int* __restrict__ labels,
    u64* __restrict__ mob, u32* __restrict__ flags,
    float* __restrict__ out)
{
    __shared__ SMem sm;

    int lane = threadIdx.x;               // block = exactly one wave
    u64 lm = (1ull << lane) - 1ull;
    int rbase = blockIdx.x * RPB;
    int img = rbase >> 10;

    // ======== phase R: reject + slow for rois [rbase, rbase+16) ========
    {
        for (int i = lane; i < NGT * 8; i += 64) sm.R.gt8[i] = gts[(size_t)img * NGT * 8 + i];
        for (int i = lane; i < RPB * 7; i += 64) sm.R.raw[i] = rois[(size_t)rbase * 7 + i];
        if (lane < RPB) sm.R.mob16[lane] = 0ull;
        __syncthreads();

        if (lane < RPB) {
            float x = sm.R.raw[lane * 7], y = sm.R.raw[lane * 7 + 1], z = sm.R.raw[lane * 7 + 2];
            float dx = sm.R.raw[lane * 7 + 3], dy = sm.R.raw[lane * 7 + 4], dz = sm.R.raw[lane * 7 + 5];
            sm.R.rx[lane] = x; sm.R.ry[lane] = y;
            sm.R.rzh[lane] = z + dz * 0.5f;
            sm.R.rzl[lane] = z - dz * 0.5f;
            sm.R.rr[lane]  = 0.5f * sqrtf(dx * dx + dy * dy);
        }
        for (int g = lane; g < NGT; g += 64) {
            float s8 = 0.f;
            #pragma unroll
            for (int q = 0; q < 8; q++) s8 += sm.R.gt8[g * 8 + q];
            float x = sm.R.gt8[g * 8], y = sm.R.gt8[g * 8 + 1], z = sm.R.gt8[g * 8 + 2];
            float dx = sm.R.gt8[g * 8 + 3], dy = sm.R.gt8[g * 8 + 4], dz = sm.R.gt8[g * 8 + 5];
            sm.R.gx[g] = x; sm.R.gy[g] = y;
            sm.R.gzh[g] = (s8 != 0.f) ? (z + dz * 0.5f) : -__builtin_huge_valf();
            sm.R.gzl[g] = z - dz * 0.5f;
            sm.R.grb[g] = 0.5f * sqrtf(dx * dx + dy * dy);
        }
        __syncthreads();

        // reject: 1600 pairs = 25 iters x 64; NO atomics (uniform register count)
        u32 cnt = 0;
        for (int iter = 0; iter < 25; iter++) {
            int idx = iter * 64 + lane;
            int rl = idx / 100;
            int g  = idx - rl * 100;
            float oh = fminf(sm.R.rzh[rl], sm.R.gzh[g]) - fmaxf(sm.R.rzl[rl], sm.R.gzl[g]);
            float ddx = sm.R.rx[rl] - sm.R.gx[g], ddy = sm.R.ry[rl] - sm.R.gy[g];
            float rr = sm.R.rr[rl] + sm.R.grb[g] + 1e-2f;
            bool sv = !(oh <= 0.0f || (ddx * ddx + ddy * ddy) > rr * rr);
            u64 m = __ballot(sv);
            if (sv) sm.R.list[cnt + (u32)__popcll(m & lm)] = (u16)((rl << 7) | g);
            cnt += (u32)__popcll(m);
        }
        __syncthreads();

        // slow path: dense over survivors (full VGPR budget, register-resident)
        for (u32 i = lane; i < cnt; i += 64) {
            u32 pid = (u32)sm.R.list[i];
            int rl = (int)(pid >> 7);
            int g  = (int)(pid & 127u);
            float a[7], b7[7];
            #pragma unroll
            for (int q = 0; q < 7; q++) a[q] = sm.R.raw[rl * 7 + q];
            #pragma unroll
            for (int q = 0; q < 7; q++) b7[q] = sm.R.gt8[g * 8 + q];
            float v = iou_slow(a, b7);
            u64 pk = (((u64)__float_as_uint(v)) << 32) | (u64)(0xFFFFFFFFu - (u32)g);
            atomicMax(&sm.R.mob16[rl], pk);   // max v, tie -> min g (verified)
        }
        __syncthreads();

        // publish mob slice, then release flag
        if (lane < RPB) mob[rbase + lane] = sm.R.mob16[lane];
        __threadfence();
        if (lane == 0)
            __hip_atomic_store(&flags[blockIdx.x], MAGIC, __ATOMIC_RELEASE, __HIP_MEMORY_SCOPE_AGENT);
    }

    // ======== election: last 8 blocks sample one image each ========
    if (blockIdx.x < GRID - 8) return;
    int simg = blockIdx.x - (GRID - 8);     // 0..7

    // wait for all 512 flags (poison 0xAAAAAAAA != MAGIC; co-residency guaranteed)
    while (true) {
        bool mine = true;
        #pragma unroll
        for (int k = 0; k < 8; k++) {
            u32 f = __hip_atomic_load(&flags[lane + k * 64], __ATOMIC_ACQUIRE, __HIP_MEMORY_SCOPE_AGENT);
            mine = mine && (f == MAGIC);
        }
        if (__ballot(mine) == ~0ull) break;
        __builtin_amdgcn_s_sleep(16);
    }
    __syncthreads();
    __threadfence();

    // ======== phase S: sampling + gather for image simg (64-thread port) ========
    {
        u32 kk[4][2];
        image_keys(simg, kk);

        // pass A: load mo, per-chunk counts (chunk ps == rois [64ps, 64ps+64))
        for (int ps = 0; ps < 16; ps++) {
            int ti = ps * 64 + lane;
            u64 mbt = mob[(size_t)simg * NM + ti];
            float mv = __uint_as_float((u32)(mbt >> 32));
            sm.S.mo[ti] = mv;
            bool fg   = (mv >= 0.55f);
            bool easy = (mv < 0.1f);
            bool hard = (mv < 0.55f) && (mv >= 0.1f);
            u64 bf = __ballot(fg), bh = __ballot(hard), be = __ballot(easy);
            if (lane == 0) {
                sm.S.wcf[ps] = __popcll(bf);
                sm.S.wch[ps] = __popcll(bh);
                sm.S.wce[ps] = __popcll(be);
            }
        }
        __syncthreads();
        if (lane == 0) {
            int af = 0, ah = 0, ae = 0;
            for (int w = 0; w < 16; w++) {
                int cf = sm.S.wcf[w], ch = sm.S.wch[w], ce = sm.S.wce[w];
                sm.S.wcf[w] = af; sm.S.wch[w] = ah; sm.S.wce[w] = ae;
                af += cf; ah += ch; ae += ce;
            }
            sm.S.nfg = af; sm.S.nhard = ah; sm.S.neasy = ae;
        }
        __syncthreads();
        // pass B: compaction (identical order to verified 1024-thread version)
        for (int ps = 0; ps < 16; ps++) {
            int ti = ps * 64 + lane;
            float mv = sm.S.mo[ti];
            bool fg   = (mv >= 0.55f);
            bool easy = (mv < 0.1f);
            bool hard = (mv < 0.55f) && (mv >= 0.1f);
            u64 bf = __ballot(fg), bh = __ballot(hard), be = __ballot(easy);
            float u1 = unif_at(kk[0], ti);      // uniform(k1,(1024,))[ti]
            if (fg)   { int p = sm.S.wcf[ps] + __popcll(bf & lm); sm.S.fgc[p] = ti; sm.S.ufg[p] = u1; }
            if (hard) { int p = sm.S.wch[ps] + __popcll(bh & lm); sm.S.hardc[p] = ti; }
            if (easy) { int p = sm.S.wce[ps] + __popcll(be & lm); sm.S.easyc[p] = ti; }
        }
        __syncthreads();

        int n_fg = sm.S.nfg, n_hard = sm.S.nhard, n_easy = sm.S.neasy;

        // fg_perm: fg indices stable-sorted by u1 (O(n_fg^2) rank)
        for (int i = lane; i < n_fg; i += 64) {
            float ut = sm.S.ufg[i];
            int rk = 0;
            for (int j = 0; j < n_fg; j++) {
                float uj = sm.S.ufg[j];
                rk += (uj < ut) || (uj == ut && j < i);
            }
            sm.S.perm[rk] = sm.S.fgc[i];
        }
        __syncthreads();

        // outputs: 128 samples in 2 passes of 64
        for (int rep = 0; rep < 2; rep++) {
            int j = rep * 64 + lane;
            int n_bg = n_hard + n_easy;
            int fg_this = (n_fg > 0) ? ((n_bg > 0) ? ((n_fg < 64) ? n_fg : 64) : 128) : 0;
            int bg_this = 128 - fg_this;

            int idx;
            if (j < fg_this) {
                if (n_bg > 0) {
                    idx = sm.S.perm[j];
                } else {
                    float u2 = unif_at(kk[1], j);
                    int v = (int)(u2 * (float)n_fg);
                    if (v > n_fg - 1) v = n_fg - 1;
                    if (v < 0) v = 0;
                    idx = sm.S.fgc[v];
                }
            } else {
                int hard_num;
                if (n_hard > 0 && n_easy > 0) hard_num = (int)((float)bg_this * 0.8f);
                else hard_num = (n_hard > 0) ? bg_this : 0;
                if (j - fg_this < hard_num) {
                    float u3 = unif_at(kk[2], j);
                    int v = (int)(u3 * (float)n_hard);
                    if (v > n_hard - 1) v = n_hard - 1;
                    if (v < 0) v = 0;
                    idx = sm.S.hardc[v];
                } else {
                    if (n_easy > 0) {
                        float u4 = unif_at(kk[3], j);
                        int v = (int)(u4 * (float)n_easy);
                        if (v > n_easy - 1) v = n_easy - 1;
                        if (v < 0) v = 0;
                        idx = sm.S.easyc[v];
                    } else {
                        idx = 0;
                    }
                }
            }
            if (idx < 0) idx = 0;
            if (idx > NM - 1) idx = NM - 1;

            float moj = sm.S.mo[idx];
            u64 mb2 = mob[(size_t)simg * NM + idx];
            u32 hi = (u32)(mb2 >> 32);
            int g = (hi == 0u) ? 0 : (int)(0xFFFFFFFFu - (u32)(mb2 & 0xFFFFFFFFull));
            if (g < 0) g = 0;
            if (g > NGT - 1) g = NGT - 1;

            size_t base = (size_t)simg * 128 + j;
            const float* rp = rois + ((size_t)simg * NM + idx) * 7;
            float* orp = out + O_ROIS + base * 7;
            for (int i = 0; i < 7; i++) orp[i] = rp[i];                // exact f32 gather

            const float* gp = gts + ((size_t)simg * NGT + g) * 8;
            float* ogp = out + O_GT + base * 8;
            for (int i = 0; i < 8; i++) ogp[i] = gp[i];                // exact f32 gather

            out[O_IOU + base] = moj;
            out[O_SC + base]  = scores[(size_t)simg * NM + idx];
            out[O_LB + base]  = (float)labels[(size_t)simg * NM + idx];

            bool cfg = moj > 0.75f, cbg = moj < 0.25f;
            float cls = (!cfg && !cbg) ? (moj * 2.0f - 0.5f) : (cfg ? 1.0f : 0.0f);
            out[O_CLS + base] = cls;
            out[O_REG + base] = (moj > 0.55f) ? 1.0f : 0.0f;
        }
    }
}

extern "C" void kernel_launch(void* const* d_in, const int* in_sizes, int n_in,
                              void* d_out, int out_size, void* d_ws, size_t ws_size,
                              hipStream_t stream) {
    // identify inputs by element count (scores/labels tie resolved in dict order)
    const float* rois   = nullptr;
    const float* gts    = nullptr;
    const float* scores = nullptr;
    const int*   labels = nullptr;
    for (int i = 0; i < n_in; i++) {
        if (in_sizes[i] == NB * NM * 7)       rois = (const float*)d_in[i];
        else if (in_sizes[i] == NB * NGT * 8) gts  = (const float*)d_in[i];
        else if (in_sizes[i] == NB * NM) {
            if (!scores) scores = (const float*)d_in[i];
            else         labels = (const int*)d_in[i];
        }
    }
    float* out = (float*)d_out;  // 20480 f32, outputs concatenated in return order

    // ws: flags u32[512] @0 | mob u64[8192] @4096. No zeroing needed:
    // flags are poison (0xAAAAAAAA != MAGIC) each launch; mob fully overwritten.
    u32* flags = (u32*)d_ws;
    u64* mob   = (u64*)((char*)d_ws + 4096);

    rcnn_fused<<<GRID, 64, 0, stream>>>(rois, gts, scores, labels, mob, flags, out);
}

// Round 15
// 87.096 us; speedup vs baseline: 1.1778x; 1.1778x over previous
//
#include <hip/hip_runtime.h>
#include <stdint.h>

#pragma clang fp contract(off)

#define NB   8
#define NM   1024
#define NGT  100
#define RPB  16                  // rois per block in K1
#define GRID (NB * NM / RPB)     // 512 blocks, image-aligned

typedef uint32_t u32;
typedef unsigned short u16;
typedef unsigned long long u64;

// ---------- Threefry-2x32 block (exact JAX schedule) ----------
__device__ __forceinline__ void tf2x32(u32 k0, u32 k1, u32 x0, u32 x1, u32& o0, u32& o1) {
    u32 k2 = k0 ^ k1 ^ 0x1BD11BDAu;
#define TFR(r) { x0 += x1; x1 = (x1 << r) | (x1 >> (32 - r)); x1 ^= x0; }
    x0 += k0; x1 += k1;
    TFR(13) TFR(15) TFR(26) TFR(6)
    x0 += k1; x1 += k2 + 1u;
    TFR(17) TFR(29) TFR(16) TFR(24)
    x0 += k2; x1 += k0 + 2u;
    TFR(13) TFR(15) TFR(26) TFR(6)
    x0 += k0; x1 += k1 + 3u;
    TFR(17) TFR(29) TFR(16) TFR(24)
    x0 += k1; x1 += k2 + 4u;
    TFR(13) TFR(15) TFR(26) TFR(6)
    x0 += k2; x1 += k0 + 5u;
#undef TFR
    o0 = x0; o1 = x1;
}

__device__ __forceinline__ u32 tf_bits32(u32 k0, u32 k1, u32 i) {
    u32 o0, o1;
    tf2x32(k0, k1, 0u, i, o0, o1);
    return o0 ^ o1;
}

__device__ __forceinline__ float bits2unif(u32 bits) {
    return __uint_as_float((bits >> 9) | 0x3f800000u) - 1.0f;
}

__device__ __forceinline__ void image_keys(int b, u32 k[4][2]) {
    u32 kb0, kb1;
    tf2x32(0u, 42u, 0u, (u32)b, kb0, kb1);               // split(key(42), 8)[b]
    for (int i = 0; i < 4; i++)
        tf2x32(kb0, kb1, 0u, (u32)i, k[i][0], k[i][1]);  // split(key_b, 4)[i]
}

__device__ __forceinline__ float unif_at(const u32 k[2], int i) {
    return bits2unif(tf_bits32(k[0], k[1], (u32)i));
}

// ---------- numpy pairwise blocked sum over exactly 24 f32 terms ----------
__device__ __forceinline__ float np_pw24(const float* t) {
    float r0 = (t[0] + t[8])  + t[16];
    float r1 = (t[1] + t[9])  + t[17];
    float r2 = (t[2] + t[10]) + t[18];
    float r3 = (t[3] + t[11]) + t[19];
    float r4 = (t[4] + t[12]) + t[20];
    float r5 = (t[5] + t[13]) + t[21];
    float r6 = (t[6] + t[14]) + t[22];
    float r7 = (t[7] + t[15]) + t[23];
    return ((r0 + r1) + (r2 + r3)) + ((r4 + r5) + (r6 + r7));
}

// monotone float -> u32 order map (no NaNs in the angle stream)
__device__ __forceinline__ u32 fkey(float f) {
    u32 b = __float_as_uint(f);
    return (b & 0x80000000u) ? ~b : (b | 0x80000000u);
}

// Batcher odd-even mergesort network, compile-time N, key + (x,y) payload
template<int N>
__device__ __forceinline__ void sortnet(u64* key, float* x, float* y) {
#define CE(A, B) { \
        u64 ka = key[A], kb = key[B]; \
        bool sw = ka > kb; \
        float xa = x[A], xb = x[B], ya = y[A], yb = y[B]; \
        key[A] = sw ? kb : ka; key[B] = sw ? ka : kb; \
        x[A]  = sw ? xb : xa; x[B]  = sw ? xa : xb; \
        y[A]  = sw ? yb : ya; y[B]  = sw ? ya : yb; }
    #pragma unroll
    for (int pp = 1; pp < N; pp <<= 1) {
        #pragma unroll
        for (int kq = pp; kq >= 1; kq >>= 1) {
            #pragma unroll
            for (int jq = kq % pp; jq + kq < N; jq += 2 * kq) {
                #pragma unroll
                for (int iq = 0; iq < kq; iq++) {
                    if (iq + jq + kq < N) {
                        if ((iq + jq) / (2 * pp) == (iq + jq + kq) / (2 * pp)) {
                            CE(iq + jq, iq + jq + kq);
                        }
                    }
                }
            }
        }
    }
#undef CE
}

// ---------- rotated 3D IoU (R10-R14 bit-verified: absmax 0.0 end-to-end) ----------
__device__ __forceinline__ float iou_slow(const float* a, const float* b) {
    float oh = fminf(a[2] + a[5] * 0.5f, b[2] + b[5] * 0.5f)
             - fmaxf(a[2] - a[5] * 0.5f, b[2] - b[5] * 0.5f);
    oh = fmaxf(oh, 0.0f);
    float va = a[3] * a[4] * a[5];
    float vb = b[3] * b[4] * b[5];

    float ca = cosf(a[6]), sa = sinf(a[6]);
    float cb = cosf(b[6]), sb = sinf(b[6]);
    const float SX[4] = {1.f, 1.f, -1.f, -1.f};
    const float SY[4] = {1.f, -1.f, -1.f, 1.f};
    float axp[4], ayp[4], bxp[4], byp[4];
    float hx = a[3] * 0.5f, hy = a[4] * 0.5f;
    #pragma unroll
    for (int q = 0; q < 4; q++) {
        float lx = SX[q] * hx, ly = SY[q] * hy;
        axp[q] = lx * ca - ly * sa + a[0];
        ayp[q] = lx * sa + ly * ca + a[1];
    }
    hx = b[3] * 0.5f; hy = b[4] * 0.5f;
    #pragma unroll
    for (int q = 0; q < 4; q++) {
        float lx = SX[q] * hx, ly = SY[q] * hy;
        bxp[q] = lx * cb - ly * sb + b[0];
        byp[q] = lx * sb + ly * cb + b[1];
    }

    float vx[24], vy[24];
    u32 vm = 0;
    #pragma unroll
    for (int i = 0; i < 4; i++) {
        float a1x = axp[i], a1y = ayp[i];
        float d1x = axp[(i + 1) & 3] - a1x, d1y = ayp[(i + 1) & 3] - a1y;
        #pragma unroll
        for (int j = 0; j < 4; j++) {
            int pos = i * 4 + j;
            float b1x = bxp[j], b1y = byp[j];
            float d2x = bxp[(j + 1) & 3] - b1x, d2y = byp[(j + 1) & 3] - b1y;
            float fx = b1x - a1x, fy = b1y - a1y;
            float den = d1x * d2y - d1y * d2x;
            bool val = false; float px = 0.f, py = 0.f;
            if (fabsf(den) > 1e-8f) {
                float tt = (fx * d2y - fy * d2x) / den;
                float uu = (fx * d1y - fy * d1x) / den;
                if (tt >= 0.f && tt <= 1.f && uu >= 0.f && uu <= 1.f) {
                    val = true; px = a1x + tt * d1x; py = a1y + tt * d1y;
                }
            }
            vx[pos] = val ? px : 0.f;
            vy[pos] = val ? py : 0.f;
            vm |= (val ? 1u : 0u) << pos;
        }
    }
    #pragma unroll
    for (int q = 0; q < 4; q++) {
        float rx = axp[q] - b[0], ry = ayp[q] - b[1];
        float lx = rx * cb + ry * sb, ly = -rx * sb + ry * cb;
        bool v = (fabsf(lx) <= b[3] * 0.5f + 1e-6f) && (fabsf(ly) <= b[4] * 0.5f + 1e-6f);
        vx[16 + q] = v ? axp[q] : 0.f; vy[16 + q] = v ? ayp[q] : 0.f;
        vm |= (v ? 1u : 0u) << (16 + q);
    }
    #pragma unroll
    for (int q = 0; q < 4; q++) {
        float rx = bxp[q] - a[0], ry = byp[q] - a[1];
        float lx = rx * ca + ry * sa, ly = -rx * sa + ry * ca;
        bool v = (fabsf(lx) <= a[3] * 0.5f + 1e-6f) && (fabsf(ly) <= a[4] * 0.5f + 1e-6f);
        vx[20 + q] = v ? bxp[q] : 0.f; vy[20 + q] = v ? bxp[q] * 0.f + byp[q] : 0.f;
        vm |= (v ? 1u : 0u) << (20 + q);
    }
    // NOTE: the line above must remain exactly vy = byp[q]; rewrite cleanly:
    #pragma unroll
    for (int q = 0; q < 4; q++) {
        if ((vm >> (20 + q)) & 1u) vy[20 + q] = byp[q];
    }

    int nv = __popc(vm);
    if (nv <= 2) return 0.0f;   // bit-exact: np pairwise shoelace of <=2 pts is 0

    float cx = np_pw24(vx) / (float)nv;
    float cy = np_pw24(vy) / (float)nv;

    float sx[24], sy[24];
    #pragma unroll
    for (int p = 0; p < 24; p++) {
        bool v = (vm >> p) & 1u;
        sx[p] = v ? (vx[p] - cx) : 0.f;
        sy[p] = v ? (vy[p] - cy) : 0.f;
    }

    float area;
    if (nv <= 8) {
        // common path: compact-to-8 (static select-gather), 8-net, ALU only
        float gx[8], gy[8]; u32 gp[8];
        #pragma unroll
        for (int i = 0; i < 8; i++) { gx[i] = 0.f; gy[i] = 0.f; gp[i] = 0u; }
        u32 pref = 0;
        #pragma unroll
        for (int p = 0; p < 24; p++) {
            bool v = (vm >> p) & 1u;
            u32 pos = pref;
            pref += v ? 1u : 0u;
            #pragma unroll
            for (int i = 0; i < 8; i++) {
                bool take = v && (pos == (u32)i);
                gx[i] += take ? sx[p] : 0.f;
                gy[i] += take ? sy[p] : 0.f;
                gp[i] |= take ? (u32)p : 0u;
            }
        }
        u64 key[8];
        #pragma unroll
        for (int i = 0; i < 8; i++) {
            float ang = atan2f(gy[i], gx[i]);
            key[i] = (i < nv) ? ((((u64)fkey(ang)) << 32) | (u64)gp[i]) : ~0ull;
        }
        sortnet<8>(key, gx, gy);
        float st[24];
        #pragma unroll
        for (int i = 0; i < 24; i++) st[i] = 0.f;
        #pragma unroll
        for (int i = 0; i < 8; i++) {
            int n1 = (i + 1 < 8) ? (i + 1) : 0;
            bool wrap = (i + 1 >= nv);
            float nx2 = wrap ? gx[0] : gx[n1];
            float ny2 = wrap ? gy[0] : gy[n1];
            float c = gx[i] * ny2 - gy[i] * nx2;
            st[i] = (i < nv) ? c : 0.0f;
        }
        area = 0.5f * fabsf(np_pw24(st));
    } else {
        // rare fallback (nv > 8): full 24-sort (R9-verified)
        u64 key[24];
        #pragma unroll
        for (int p = 0; p < 24; p++) {
            bool v = (vm >> p) & 1u;
            float ang = atan2f(sy[p], sx[p]);
            u32 hi = v ? fkey(ang) : 0xFFFFFFFFu;
            key[p] = ((u64)hi << 32) | (u64)(u32)p;
        }
        sortnet<24>(key, sx, sy);
        float st[24];
        #pragma unroll
        for (int i = 0; i < 24; i++) {
            const int nidx = (i + 1 < 24) ? (i + 1) : 0;
            bool wrap = (i + 1 >= nv);
            float nx2 = wrap ? sx[0] : sx[nidx];
            float ny2 = wrap ? sy[0] : sy[nidx];
            float c = sx[i] * ny2 - sy[i] * nx2;
            st[i] = (i < nv) ? c : 0.0f;
        }
        area = 0.5f * fabsf(np_pw24(st));
    }
    float inter = area * oh;
    return inter / fmaxf(va + vb - inter, 1e-6f);
}

// ---------- K1: reject + slow path, 512 blocks x 64 thr (R14 phase R verbatim) ----------
__global__ __launch_bounds__(64, 1) void iou_kernel(
    const float* __restrict__ rois, const float* __restrict__ gts,
    u64* __restrict__ mob)
{
    __shared__ float s_gt8[NGT * 8];
    __shared__ float s_raw[RPB * 7];
    __shared__ float s_gx[NGT], s_gy[NGT], s_gzh[NGT], s_gzl[NGT], s_grb[NGT];
    __shared__ float s_rx[RPB], s_ry[RPB], s_rzh[RPB], s_rzl[RPB], s_rr[RPB];
    __shared__ u16   s_list[RPB * NGT];
    __shared__ u64   s_mob16[RPB];

    int lane = threadIdx.x;               // block = exactly one wave
    u64 lm = (1ull << lane) - 1ull;
    int rbase = blockIdx.x * RPB;
    int img = rbase >> 10;

    for (int i = lane; i < NGT * 8; i += 64) s_gt8[i] = gts[(size_t)img * NGT * 8 + i];
    for (int i = lane; i < RPB * 7; i += 64) s_raw[i] = rois[(size_t)rbase * 7 + i];
    if (lane < RPB) s_mob16[lane] = 0ull;
    __syncthreads();

    if (lane < RPB) {
        float x = s_raw[lane * 7], y = s_raw[lane * 7 + 1], z = s_raw[lane * 7 + 2];
        float dx = s_raw[lane * 7 + 3], dy = s_raw[lane * 7 + 4], dz = s_raw[lane * 7 + 5];
        s_rx[lane] = x; s_ry[lane] = y;
        s_rzh[lane] = z + dz * 0.5f;
        s_rzl[lane] = z - dz * 0.5f;
        s_rr[lane]  = 0.5f * sqrtf(dx * dx + dy * dy);
    }
    for (int g = lane; g < NGT; g += 64) {
        float s8 = 0.f;
        #pragma unroll
        for (int q = 0; q < 8; q++) s8 += s_gt8[g * 8 + q];
        float x = s_gt8[g * 8], y = s_gt8[g * 8 + 1], z = s_gt8[g * 8 + 2];
        float dx = s_gt8[g * 8 + 3], dy = s_gt8[g * 8 + 4], dz = s_gt8[g * 8 + 5];
        s_gx[g] = x; s_gy[g] = y;
        s_gzh[g] = (s8 != 0.f) ? (z + dz * 0.5f) : -__builtin_huge_valf();
        s_gzl[g] = z - dz * 0.5f;
        s_grb[g] = 0.5f * sqrtf(dx * dx + dy * dy);
    }
    __syncthreads();

    // reject: 1600 pairs = 25 iters x 64; NO atomics (uniform register count)
    u32 cnt = 0;
    for (int iter = 0; iter < 25; iter++) {
        int idx = iter * 64 + lane;
        int rl = idx / 100;
        int g  = idx - rl * 100;
        float oh = fminf(s_rzh[rl], s_gzh[g]) - fmaxf(s_rzl[rl], s_gzl[g]);
        float ddx = s_rx[rl] - s_gx[g], ddy = s_ry[rl] - s_gy[g];
        float rr = s_rr[rl] + s_grb[g] + 1e-2f;
        bool sv = !(oh <= 0.0f || (ddx * ddx + ddy * ddy) > rr * rr);
        u64 m = __ballot(sv);
        if (sv) s_list[cnt + (u32)__popcll(m & lm)] = (u16)((rl << 7) | g);
        cnt += (u32)__popcll(m);
    }
    __syncthreads();

    // slow path: dense over survivors
    for (u32 i = lane; i < cnt; i += 64) {
        u32 pid = (u32)s_list[i];
        int rl = (int)(pid >> 7);
        int g  = (int)(pid & 127u);
        float a[7], b7[7];
        #pragma unroll
        for (int q = 0; q < 7; q++) a[q] = s_raw[rl * 7 + q];
        #pragma unroll
        for (int q = 0; q < 7; q++) b7[q] = s_gt8[g * 8 + q];
        float v = iou_slow(a, b7);
        u64 pk = (((u64)__float_as_uint(v)) << 32) | (u64)(0xFFFFFFFFu - (u32)g);
        atomicMax(&s_mob16[rl], pk);      // max v, tie -> min g (verified)
    }
    __syncthreads();

    if (lane < RPB) mob[rbase + lane] = s_mob16[lane];
}

// ---------- K2: per-image sampling + gather (R13-verified, 8 x 1024) ----------
#define O_ROIS 0
#define O_GT   7168
#define O_IOU  15360
#define O_SC   16384
#define O_LB   17408
#define O_CLS  18432
#define O_REG  19456

__global__ __launch_bounds__(1024) void sample_kernel(
    const float* __restrict__ rois, const float* __restrict__ gts,
    const float* __restrict__ scores, const int* __restrict__ labels,
    const u64* __restrict__ mob, float* __restrict__ out)
{
    __shared__ float s_mo[NM];
    __shared__ float s_ufg[NM];
    __shared__ int   s_fgc[NM], s_hardc[NM], s_easyc[NM], s_perm[NM];
    __shared__ int   s_wcf[16], s_wch[16], s_wce[16];
    __shared__ int   s_nfg, s_nhard, s_neasy;

    int img = blockIdx.x;
    int t = threadIdx.x;
    int lane = t & 63, wid = t >> 6;
    u64 lm = (1ull << lane) - 1ull;

    u32 kk[4][2];
    image_keys(img, kk);

    u64 mbt = mob[(size_t)img * NM + t];
    float mv = __uint_as_float((u32)(mbt >> 32));
    s_mo[t] = mv;
    bool fg   = (mv >= 0.55f);
    bool easy = (mv < 0.1f);
    bool hard = (mv < 0.55f) && (mv >= 0.1f);

    float u1 = unif_at(kk[0], t);   // uniform(k1, (1024,))[t]

    u64 bf_ = __ballot(fg);
    u64 bh_ = __ballot(hard);
    u64 be_ = __ballot(easy);
    if (lane == 0) {
        s_wcf[wid] = __popcll(bf_);
        s_wch[wid] = __popcll(bh_);
        s_wce[wid] = __popcll(be_);
    }
    __syncthreads();
    if (t == 0) {
        int af = 0, ah = 0, ae = 0;
        for (int w = 0; w < 16; w++) {
            int cf = s_wcf[w], ch = s_wch[w], ce = s_wce[w];
            s_wcf[w] = af; s_wch[w] = ah; s_wce[w] = ae;
            af += cf; ah += ch; ae += ce;
        }
        s_nfg = af; s_nhard = ah; s_neasy = ae;
    }
    __syncthreads();
    if (fg)   { int p = s_wcf[wid] + __popcll(bf_ & lm); s_fgc[p] = t; s_ufg[p] = u1; }
    if (hard) { int p = s_wch[wid] + __popcll(bh_ & lm); s_hardc[p] = t; }
    if (easy) { int p = s_wce[wid] + __popcll(be_ & lm); s_easyc[p] = t; }
    __syncthreads();

    int n_fg = s_nfg, n_hard = s_nhard, n_easy = s_neasy;

    // fg_perm: fg indices stable-sorted by u1 (O(n_fg^2) rank)
    if (t < n_fg) {
        float ut = s_ufg[t];
        int rk = 0;
        for (int j = 0; j < n_fg; j++) {
            float uj = s_ufg[j];
            rk += (uj < ut) || (uj == ut && j < t);
        }
        s_perm[rk] = s_fgc[t];
    }
    __syncthreads();

    if (t < 128) {
        int j = t;
        int n_bg = n_hard + n_easy;
        int fg_this = (n_fg > 0) ? ((n_bg > 0) ? ((n_fg < 64) ? n_fg : 64) : 128) : 0;
        int bg_this = 128 - fg_this;

        int idx;
        if (j < fg_this) {
            if (n_bg > 0) {
                idx = s_perm[j];
            } else {
                float u2 = unif_at(kk[1], j);
                int v = (int)(u2 * (float)n_fg);
                if (v > n_fg - 1) v = n_fg - 1;
                if (v < 0) v = 0;
                idx = s_fgc[v];
            }
        } else {
            int hard_num;
            if (n_hard > 0 && n_easy > 0) hard_num = (int)((float)bg_this * 0.8f);
            else hard_num = (n_hard > 0) ? bg_this : 0;
            if (j - fg_this < hard_num) {
                float u3 = unif_at(kk[2], j);
                int v = (int)(u3 * (float)n_hard);
                if (v > n_hard - 1) v = n_hard - 1;
                if (v < 0) v = 0;
                idx = s_hardc[v];
            } else {
                if (n_easy > 0) {
                    float u4 = unif_at(kk[3], j);
                    int v = (int)(u4 * (float)n_easy);
                    if (v > n_easy - 1) v = n_easy - 1;
                    if (v < 0) v = 0;
                    idx = s_easyc[v];
                } else {
                    idx = 0;
                }
            }
        }
        if (idx < 0) idx = 0;
        if (idx > NM - 1) idx = NM - 1;

        float moj = s_mo[idx];
        u64 mb2 = mob[(size_t)img * NM + idx];
        u32 hi = (u32)(mb2 >> 32);
        int g = (hi == 0u) ? 0 : (int)(0xFFFFFFFFu - (u32)(mb2 & 0xFFFFFFFFull));
        if (g < 0) g = 0;
        if (g > NGT - 1) g = NGT - 1;

        size_t base = (size_t)img * 128 + j;
        const float* rp = rois + ((size_t)img * NM + idx) * 7;
        float* orp = out + O_ROIS + base * 7;
        for (int i = 0; i < 7; i++) orp[i] = rp[i];                    // exact f32 gather

        const float* gp = gts + ((size_t)img * NGT + g) * 8;
        float* ogp = out + O_GT + base * 8;
        for (int i = 0; i < 8; i++) ogp[i] = gp[i];                    // exact f32 gather

        out[O_IOU + base] = moj;
        out[O_SC + base]  = scores[(size_t)img * NM + idx];
        out[O_LB + base]  = (float)labels[(size_t)img * NM + idx];

        bool cfg = moj > 0.75f, cbg = moj < 0.25f;
        float cls = (!cfg && !cbg) ? (moj * 2.0f - 0.5f) : (cfg ? 1.0f : 0.0f);
        out[O_CLS + base] = cls;
        out[O_REG + base] = (moj > 0.55f) ? 1.0f : 0.0f;
    }
}

extern "C" void kernel_launch(void* const* d_in, const int* in_sizes, int n_in,
                              void* d_out, int out_size, void* d_ws, size_t ws_size,
                              hipStream_t stream) {
    // identify inputs by element count (scores/labels tie resolved in dict order)
    const float* rois   = nullptr;
    const float* gts    = nullptr;
    const float* scores = nullptr;
    const int*   labels = nullptr;
    for (int i = 0; i < n_in; i++) {
        if (in_sizes[i] == NB * NM * 7)       rois = (const float*)d_in[i];
        else if (in_sizes[i] == NB * NGT * 8) gts  = (const float*)d_in[i];
        else if (in_sizes[i] == NB * NM) {
            if (!scores) scores = (const float*)d_in[i];
            else         labels = (const int*)d_in[i];
        }
    }
    float* out = (float*)d_out;  // 20480 f32, outputs concatenated in return order

    // ws: mob u64[8192] @0 — fully written by K1 each launch, no zeroing needed
    u64* mob = (u64*)d_ws;

    iou_kernel<<<GRID, 64, 0, stream>>>(rois, gts, mob);
    sample_kernel<<<NB, 1024, 0, stream>>>(rois, gts, scores, labels, mob, out);
}

// Round 16
// 84.998 us; speedup vs baseline: 1.2069x; 1.0247x over previous
//
#include <hip/hip_runtime.h>
#include <stdint.h>

#pragma clang fp contract(off)

#define NB   8
#define NM   1024
#define NGT  100
#define RPB  4                   // rois per block in K1 (R16: 16 -> 4 for 4x occupancy)
#define GRID (NB * NM / RPB)     // 2048 blocks, image-aligned
#define NPAIRS (RPB * NGT)       // 400
#define RITERS ((NPAIRS + 63) / 64)  // 7

typedef uint32_t u32;
typedef unsigned short u16;
typedef unsigned long long u64;

// ---------- Threefry-2x32 block (exact JAX schedule) ----------
__device__ __forceinline__ void tf2x32(u32 k0, u32 k1, u32 x0, u32 x1, u32& o0, u32& o1) {
    u32 k2 = k0 ^ k1 ^ 0x1BD11BDAu;
#define TFR(r) { x0 += x1; x1 = (x1 << r) | (x1 >> (32 - r)); x1 ^= x0; }
    x0 += k0; x1 += k1;
    TFR(13) TFR(15) TFR(26) TFR(6)
    x0 += k1; x1 += k2 + 1u;
    TFR(17) TFR(29) TFR(16) TFR(24)
    x0 += k2; x1 += k0 + 2u;
    TFR(13) TFR(15) TFR(26) TFR(6)
    x0 += k0; x1 += k1 + 3u;
    TFR(17) TFR(29) TFR(16) TFR(24)
    x0 += k1; x1 += k2 + 4u;
    TFR(13) TFR(15) TFR(26) TFR(6)
    x0 += k2; x1 += k0 + 5u;
#undef TFR
    o0 = x0; o1 = x1;
}

__device__ __forceinline__ u32 tf_bits32(u32 k0, u32 k1, u32 i) {
    u32 o0, o1;
    tf2x32(k0, k1, 0u, i, o0, o1);
    return o0 ^ o1;
}

__device__ __forceinline__ float bits2unif(u32 bits) {
    return __uint_as_float((bits >> 9) | 0x3f800000u) - 1.0f;
}

__device__ __forceinline__ void image_keys(int b, u32 k[4][2]) {
    u32 kb0, kb1;
    tf2x32(0u, 42u, 0u, (u32)b, kb0, kb1);               // split(key(42), 8)[b]
    for (int i = 0; i < 4; i++)
        tf2x32(kb0, kb1, 0u, (u32)i, k[i][0], k[i][1]);  // split(key_b, 4)[i]
}

__device__ __forceinline__ float unif_at(const u32 k[2], int i) {
    return bits2unif(tf_bits32(k[0], k[1], (u32)i));
}

// ---------- numpy pairwise blocked sum over exactly 24 f32 terms ----------
__device__ __forceinline__ float np_pw24(const float* t) {
    float r0 = (t[0] + t[8])  + t[16];
    float r1 = (t[1] + t[9])  + t[17];
    float r2 = (t[2] + t[10]) + t[18];
    float r3 = (t[3] + t[11]) + t[19];
    float r4 = (t[4] + t[12]) + t[20];
    float r5 = (t[5] + t[13]) + t[21];
    float r6 = (t[6] + t[14]) + t[22];
    float r7 = (t[7] + t[15]) + t[23];
    return ((r0 + r1) + (r2 + r3)) + ((r4 + r5) + (r6 + r7));
}

// monotone float -> u32 order map (no NaNs in the angle stream)
__device__ __forceinline__ u32 fkey(float f) {
    u32 b = __float_as_uint(f);
    return (b & 0x80000000u) ? ~b : (b | 0x80000000u);
}

// Batcher odd-even mergesort network, compile-time N, key + (x,y) payload
template<int N>
__device__ __forceinline__ void sortnet(u64* key, float* x, float* y) {
#define CE(A, B) { \
        u64 ka = key[A], kb = key[B]; \
        bool sw = ka > kb; \
        float xa = x[A], xb = x[B], ya = y[A], yb = y[B]; \
        key[A] = sw ? kb : ka; key[B] = sw ? ka : kb; \
        x[A]  = sw ? xb : xa; x[B]  = sw ? xa : xb; \
        y[A]  = sw ? yb : ya; y[B]  = sw ? ya : yb; }
    #pragma unroll
    for (int pp = 1; pp < N; pp <<= 1) {
        #pragma unroll
        for (int kq = pp; kq >= 1; kq >>= 1) {
            #pragma unroll
            for (int jq = kq % pp; jq + kq < N; jq += 2 * kq) {
                #pragma unroll
                for (int iq = 0; iq < kq; iq++) {
                    if (iq + jq + kq < N) {
                        if ((iq + jq) / (2 * pp) == (iq + jq + kq) / (2 * pp)) {
                            CE(iq + jq, iq + jq + kq);
                        }
                    }
                }
            }
        }
    }
#undef CE
}

// ---------- rotated 3D IoU (R10-R15 bit-verified: absmax 0.0 end-to-end) ----------
__device__ __forceinline__ float iou_slow(const float* a, const float* b) {
    float oh = fminf(a[2] + a[5] * 0.5f, b[2] + b[5] * 0.5f)
             - fmaxf(a[2] - a[5] * 0.5f, b[2] - b[5] * 0.5f);
    oh = fmaxf(oh, 0.0f);
    float va = a[3] * a[4] * a[5];
    float vb = b[3] * b[4] * b[5];

    float ca = cosf(a[6]), sa = sinf(a[6]);
    float cb = cosf(b[6]), sb = sinf(b[6]);
    const float SX[4] = {1.f, 1.f, -1.f, -1.f};
    const float SY[4] = {1.f, -1.f, -1.f, 1.f};
    float axp[4], ayp[4], bxp[4], byp[4];
    float hx = a[3] * 0.5f, hy = a[4] * 0.5f;
    #pragma unroll
    for (int q = 0; q < 4; q++) {
        float lx = SX[q] * hx, ly = SY[q] * hy;
        axp[q] = lx * ca - ly * sa + a[0];
        ayp[q] = lx * sa + ly * ca + a[1];
    }
    hx = b[3] * 0.5f; hy = b[4] * 0.5f;
    #pragma unroll
    for (int q = 0; q < 4; q++) {
        float lx = SX[q] * hx, ly = SY[q] * hy;
        bxp[q] = lx * cb - ly * sb + b[0];
        byp[q] = lx * sb + ly * cb + b[1];
    }

    float vx[24], vy[24];
    u32 vm = 0;
    #pragma unroll
    for (int i = 0; i < 4; i++) {
        float a1x = axp[i], a1y = ayp[i];
        float d1x = axp[(i + 1) & 3] - a1x, d1y = ayp[(i + 1) & 3] - a1y;
        #pragma unroll
        for (int j = 0; j < 4; j++) {
            int pos = i * 4 + j;
            float b1x = bxp[j], b1y = byp[j];
            float d2x = bxp[(j + 1) & 3] - b1x, d2y = byp[(j + 1) & 3] - b1y;
            float fx = b1x - a1x, fy = b1y - a1y;
            float den = d1x * d2y - d1y * d2x;
            bool val = false; float px = 0.f, py = 0.f;
            if (fabsf(den) > 1e-8f) {
                float tt = (fx * d2y - fy * d2x) / den;
                float uu = (fx * d1y - fy * d1x) / den;
                if (tt >= 0.f && tt <= 1.f && uu >= 0.f && uu <= 1.f) {
                    val = true; px = a1x + tt * d1x; py = a1y + tt * d1y;
                }
            }
            vx[pos] = val ? px : 0.f;
            vy[pos] = val ? py : 0.f;
            vm |= (val ? 1u : 0u) << pos;
        }
    }
    #pragma unroll
    for (int q = 0; q < 4; q++) {
        float rx = axp[q] - b[0], ry = ayp[q] - b[1];
        float lx = rx * cb + ry * sb, ly = -rx * sb + ry * cb;
        bool v = (fabsf(lx) <= b[3] * 0.5f + 1e-6f) && (fabsf(ly) <= b[4] * 0.5f + 1e-6f);
        vx[16 + q] = v ? axp[q] : 0.f; vy[16 + q] = v ? ayp[q] : 0.f;
        vm |= (v ? 1u : 0u) << (16 + q);
    }
    #pragma unroll
    for (int q = 0; q < 4; q++) {
        float rx = bxp[q] - a[0], ry = byp[q] - a[1];
        float lx = rx * ca + ry * sa, ly = -rx * sa + ry * ca;
        bool v = (fabsf(lx) <= a[3] * 0.5f + 1e-6f) && (fabsf(ly) <= a[4] * 0.5f + 1e-6f);
        vx[20 + q] = v ? bxp[q] : 0.f; vy[20 + q] = v ? bxp[q] * 0.f + byp[q] : 0.f;
        vm |= (v ? 1u : 0u) << (20 + q);
    }
    // NOTE: kept verbatim from verified R15 (vy rewrite below makes it byp[q] exactly)
    #pragma unroll
    for (int q = 0; q < 4; q++) {
        if ((vm >> (20 + q)) & 1u) vy[20 + q] = byp[q];
    }

    int nv = __popc(vm);
    if (nv <= 2) return 0.0f;   // bit-exact: np pairwise shoelace of <=2 pts is 0

    float cx = np_pw24(vx) / (float)nv;
    float cy = np_pw24(vy) / (float)nv;

    float sx[24], sy[24];
    #pragma unroll
    for (int p = 0; p < 24; p++) {
        bool v = (vm >> p) & 1u;
        sx[p] = v ? (vx[p] - cx) : 0.f;
        sy[p] = v ? (vy[p] - cy) : 0.f;
    }

    float area;
    if (nv <= 8) {
        // common path: compact-to-8 (static select-gather), 8-net, ALU only
        float gx[8], gy[8]; u32 gp[8];
        #pragma unroll
        for (int i = 0; i < 8; i++) { gx[i] = 0.f; gy[i] = 0.f; gp[i] = 0u; }
        u32 pref = 0;
        #pragma unroll
        for (int p = 0; p < 24; p++) {
            bool v = (vm >> p) & 1u;
            u32 pos = pref;
            pref += v ? 1u : 0u;
            #pragma unroll
            for (int i = 0; i < 8; i++) {
                bool take = v && (pos == (u32)i);
                gx[i] += take ? sx[p] : 0.f;
                gy[i] += take ? sy[p] : 0.f;
                gp[i] |= take ? (u32)p : 0u;
            }
        }
        u64 key[8];
        #pragma unroll
        for (int i = 0; i < 8; i++) {
            float ang = atan2f(gy[i], gx[i]);
            key[i] = (i < nv) ? ((((u64)fkey(ang)) << 32) | (u64)gp[i]) : ~0ull;
        }
        sortnet<8>(key, gx, gy);
        float st[24];
        #pragma unroll
        for (int i = 0; i < 24; i++) st[i] = 0.f;
        #pragma unroll
        for (int i = 0; i < 8; i++) {
            int n1 = (i + 1 < 8) ? (i + 1) : 0;
            bool wrap = (i + 1 >= nv);
            float nx2 = wrap ? gx[0] : gx[n1];
            float ny2 = wrap ? gy[0] : gy[n1];
            float c = gx[i] * ny2 - gy[i] * nx2;
            st[i] = (i < nv) ? c : 0.0f;
        }
        area = 0.5f * fabsf(np_pw24(st));
    } else {
        // rare fallback (nv > 8): full 24-sort (R9-verified)
        u64 key[24];
        #pragma unroll
        for (int p = 0; p < 24; p++) {
            bool v = (vm >> p) & 1u;
            float ang = atan2f(sy[p], sx[p]);
            u32 hi = v ? fkey(ang) : 0xFFFFFFFFu;
            key[p] = ((u64)hi << 32) | (u64)(u32)p;
        }
        sortnet<24>(key, sx, sy);
        float st[24];
        #pragma unroll
        for (int i = 0; i < 24; i++) {
            const int nidx = (i + 1 < 24) ? (i + 1) : 0;
            bool wrap = (i + 1 >= nv);
            float nx2 = wrap ? sx[0] : sx[nidx];
            float ny2 = wrap ? sy[0] : sy[nidx];
            float c = sx[i] * ny2 - sy[i] * nx2;
            st[i] = (i < nv) ? c : 0.0f;
        }
        area = 0.5f * fabsf(np_pw24(st));
    }
    float inter = area * oh;
    return inter / fmaxf(va + vb - inter, 1e-6f);
}

// ---------- K1: reject + slow path, 2048 blocks x 64 thr ----------
__global__ __launch_bounds__(64, 1) void iou_kernel(
    const float* __restrict__ rois, const float* __restrict__ gts,
    u64* __restrict__ mob)
{
    __shared__ float s_gt8[NGT * 8];
    __shared__ float s_raw[RPB * 7];
    __shared__ float s_gx[NGT], s_gy[NGT], s_gzh[NGT], s_gzl[NGT], s_grb[NGT];
    __shared__ float s_rx[RPB], s_ry[RPB], s_rzh[RPB], s_rzl[RPB], s_rr[RPB];
    __shared__ u16   s_list[NPAIRS];
    __shared__ u64   s_mob16[RPB];

    int lane = threadIdx.x;               // block = exactly one wave
    u64 lm = (1ull << lane) - 1ull;
    int rbase = blockIdx.x * RPB;
    int img = rbase >> 10;

    for (int i = lane; i < NGT * 8; i += 64) s_gt8[i] = gts[(size_t)img * NGT * 8 + i];
    for (int i = lane; i < RPB * 7; i += 64) s_raw[i] = rois[(size_t)rbase * 7 + i];
    if (lane < RPB) s_mob16[lane] = 0ull;
    __syncthreads();

    if (lane < RPB) {
        float x = s_raw[lane * 7], y = s_raw[lane * 7 + 1], z = s_raw[lane * 7 + 2];
        float dx = s_raw[lane * 7 + 3], dy = s_raw[lane * 7 + 4], dz = s_raw[lane * 7 + 5];
        s_rx[lane] = x; s_ry[lane] = y;
        s_rzh[lane] = z + dz * 0.5f;
        s_rzl[lane] = z - dz * 0.5f;
        s_rr[lane]  = 0.5f * sqrtf(dx * dx + dy * dy);
    }
    for (int g = lane; g < NGT; g += 64) {
        float s8 = 0.f;
        #pragma unroll
        for (int q = 0; q < 8; q++) s8 += s_gt8[g * 8 + q];
        float x = s_gt8[g * 8], y = s_gt8[g * 8 + 1], z = s_gt8[g * 8 + 2];
        float dx = s_gt8[g * 8 + 3], dy = s_gt8[g * 8 + 4], dz = s_gt8[g * 8 + 5];
        s_gx[g] = x; s_gy[g] = y;
        s_gzh[g] = (s8 != 0.f) ? (z + dz * 0.5f) : -__builtin_huge_valf();
        s_gzl[g] = z - dz * 0.5f;
        s_grb[g] = 0.5f * sqrtf(dx * dx + dy * dy);
    }
    __syncthreads();

    // reject: NPAIRS pairs in RITERS x 64 lanes (tail predicated); NO atomics
    u32 cnt = 0;
    for (int iter = 0; iter < RITERS; iter++) {
        int idx = iter * 64 + lane;
        bool inb = idx < NPAIRS;
        int ci = inb ? idx : 0;
        int rl = ci / 100;
        int g  = ci - rl * 100;
        float oh = fminf(s_rzh[rl], s_gzh[g]) - fmaxf(s_rzl[rl], s_gzl[g]);
        float ddx = s_rx[rl] - s_gx[g], ddy = s_ry[rl] - s_gy[g];
        float rr = s_rr[rl] + s_grb[g] + 1e-2f;
        bool sv = inb && !(oh <= 0.0f || (ddx * ddx + ddy * ddy) > rr * rr);
        u64 m = __ballot(sv);
        if (sv) s_list[cnt + (u32)__popcll(m & lm)] = (u16)((rl << 7) | g);
        cnt += (u32)__popcll(m);
    }
    __syncthreads();

    // slow path: dense over survivors (register-resident common path)
    for (u32 i = lane; i < cnt; i += 64) {
        u32 pid = (u32)s_list[i];
        int rl = (int)(pid >> 7);
        int g  = (int)(pid & 127u);
        float a[7], b7[7];
        #pragma unroll
        for (int q = 0; q < 7; q++) a[q] = s_raw[rl * 7 + q];
        #pragma unroll
        for (int q = 0; q < 7; q++) b7[q] = s_gt8[g * 8 + q];
        float v = iou_slow(a, b7);
        u64 pk = (((u64)__float_as_uint(v)) << 32) | (u64)(0xFFFFFFFFu - (u32)g);
        atomicMax(&s_mob16[rl], pk);      // max v, tie -> min g (verified)
    }
    __syncthreads();

    if (lane < RPB) mob[rbase + lane] = s_mob16[lane];
}

// ---------- K2: per-image sampling + gather (R13/R15-verified, 8 x 1024) ----------
#define O_ROIS 0
#define O_GT   7168
#define O_IOU  15360
#define O_SC   16384
#define O_LB   17408
#define O_CLS  18432
#define O_REG  19456

__global__ __launch_bounds__(1024) void sample_kernel(
    const float* __restrict__ rois, const float* __restrict__ gts,
    const float* __restrict__ scores, const int* __restrict__ labels,
    const u64* __restrict__ mob, float* __restrict__ out)
{
    __shared__ float s_mo[NM];
    __shared__ float s_ufg[NM];
    __shared__ int   s_fgc[NM], s_hardc[NM], s_easyc[NM], s_perm[NM];
    __shared__ int   s_wcf[16], s_wch[16], s_wce[16];
    __shared__ int   s_nfg, s_nhard, s_neasy;

    int img = blockIdx.x;
    int t = threadIdx.x;
    int lane = t & 63, wid = t >> 6;
    u64 lm = (1ull << lane) - 1ull;

    u32 kk[4][2];
    image_keys(img, kk);

    u64 mbt = mob[(size_t)img * NM + t];
    float mv = __uint_as_float((u32)(mbt >> 32));
    s_mo[t] = mv;
    bool fg   = (mv >= 0.55f);
    bool easy = (mv < 0.1f);
    bool hard = (mv < 0.55f) && (mv >= 0.1f);

    float u1 = unif_at(kk[0], t);   // uniform(k1, (1024,))[t]

    u64 bf_ = __ballot(fg);
    u64 bh_ = __ballot(hard);
    u64 be_ = __ballot(easy);
    if (lane == 0) {
        s_wcf[wid] = __popcll(bf_);
        s_wch[wid] = __popcll(bh_);
        s_wce[wid] = __popcll(be_);
    }
    __syncthreads();
    if (t == 0) {
        int af = 0, ah = 0, ae = 0;
        for (int w = 0; w < 16; w++) {
            int cf = s_wcf[w], ch = s_wch[w], ce = s_wce[w];
            s_wcf[w] = af; s_wch[w] = ah; s_wce[w] = ae;
            af += cf; ah += ch; ae += ce;
        }
        s_nfg = af; s_nhard = ah; s_neasy = ae;
    }
    __syncthreads();
    if (fg)   { int p = s_wcf[wid] + __popcll(bf_ & lm); s_fgc[p] = t; s_ufg[p] = u1; }
    if (hard) { int p = s_wch[wid] + __popcll(bh_ & lm); s_hardc[p] = t; }
    if (easy) { int p = s_wce[wid] + __popcll(be_ & lm); s_easyc[p] = t; }
    __syncthreads();

    int n_fg = s_nfg, n_hard = s_nhard, n_easy = s_neasy;

    // fg_perm: fg indices stable-sorted by u1 (O(n_fg^2) rank)
    if (t < n_fg) {
        float ut = s_ufg[t];
        int rk = 0;
        for (int j = 0; j < n_fg; j++) {
            float uj = s_ufg[j];
            rk += (uj < ut) || (uj == ut && j < t);
        }
        s_perm[rk] = s_fgc[t];
    }
    __syncthreads();

    if (t < 128) {
        int j = t;
        int n_bg = n_hard + n_easy;
        int fg_this = (n_fg > 0) ? ((n_bg > 0) ? ((n_fg < 64) ? n_fg : 64) : 128) : 0;
        int bg_this = 128 - fg_this;

        int idx;
        if (j < fg_this) {
            if (n_bg > 0) {
                idx = s_perm[j];
            } else {
                float u2 = unif_at(kk[1], j);
                int v = (int)(u2 * (float)n_fg);
                if (v > n_fg - 1) v = n_fg - 1;
                if (v < 0) v = 0;
                idx = s_fgc[v];
            }
        } else {
            int hard_num;
            if (n_hard > 0 && n_easy > 0) hard_num = (int)((float)bg_this * 0.8f);
            else hard_num = (n_hard > 0) ? bg_this : 0;
            if (j - fg_this < hard_num) {
                float u3 = unif_at(kk[2], j);
                int v = (int)(u3 * (float)n_hard);
                if (v > n_hard - 1) v = n_hard - 1;
                if (v < 0) v = 0;
                idx = s_hardc[v];
            } else {
                if (n_easy > 0) {
                    float u4 = unif_at(kk[3], j);
                    int v = (int)(u4 * (float)n_easy);
                    if (v > n_easy - 1) v = n_easy - 1;
                    if (v < 0) v = 0;
                    idx = s_easyc[v];
                } else {
                    idx = 0;
                }
            }
        }
        if (idx < 0) idx = 0;
        if (idx > NM - 1) idx = NM - 1;

        float moj = s_mo[idx];
        u64 mb2 = mob[(size_t)img * NM + idx];
        u32 hi = (u32)(mb2 >> 32);
        int g = (hi == 0u) ? 0 : (int)(0xFFFFFFFFu - (u32)(mb2 & 0xFFFFFFFFull));
        if (g < 0) g = 0;
        if (g > NGT - 1) g = NGT - 1;

        size_t base = (size_t)img * 128 + j;
        const float* rp = rois + ((size_t)img * NM + idx) * 7;
        float* orp = out + O_ROIS + base * 7;
        for (int i = 0; i < 7; i++) orp[i] = rp[i];                    // exact f32 gather

        const float* gp = gts + ((size_t)img * NGT + g) * 8;
        float* ogp = out + O_GT + base * 8;
        for (int i = 0; i < 8; i++) ogp[i] = gp[i];                    // exact f32 gather

        out[O_IOU + base] = moj;
        out[O_SC + base]  = scores[(size_t)img * NM + idx];
        out[O_LB + base]  = (float)labels[(size_t)img * NM + idx];

        bool cfg = moj > 0.75f, cbg = moj < 0.25f;
        float cls = (!cfg && !cbg) ? (moj * 2.0f - 0.5f) : (cfg ? 1.0f : 0.0f);
        out[O_CLS + base] = cls;
        out[O_REG + base] = (moj > 0.55f) ? 1.0f : 0.0f;
    }
}

extern "C" void kernel_launch(void* const* d_in, const int* in_sizes, int n_in,
                              void* d_out, int out_size, void* d_ws, size_t ws_size,
                              hipStream_t stream) {
    // identify inputs by element count (scores/labels tie resolved in dict order)
    const float* rois   = nullptr;
    const float* gts    = nullptr;
    const float* scores = nullptr;
    const int*   labels = nullptr;
    for (int i = 0; i < n_in; i++) {
        if (in_sizes[i] == NB * NM * 7)       rois = (const float*)d_in[i];
        else if (in_sizes[i] == NB * NGT * 8) gts  = (const float*)d_in[i];
        else if (in_sizes[i] == NB * NM) {
            if (!scores) scores = (const float*)d_in[i];
            else         labels = (const int*)d_in[i];
        }
    }
    float* out = (float*)d_out;  // 20480 f32, outputs concatenated in return order

    // ws: mob u64[8192] @0 — fully written by K1 each launch, no zeroing needed
    u64* mob = (u64*)d_ws;

    iou_kernel<<<GRID, 64, 0, stream>>>(rois, gts, mob);
    sample_kernel<<<NB, 1024, 0, stream>>>(rois, gts, scores, labels, mob, out);
}